// Round 10
// baseline (252.562 us; speedup 1.0000x reference)
//
#include <hip/hip_runtime.h>
#include <hip/hip_bf16.h>
#include <math.h>

#define BB 2
#define SS 2048
#define DMM 1024
#define HH 16
#define HDD 64
#define NGLOB 32
#define MM 4096   // B*S

typedef __attribute__((ext_vector_type(8))) short short8;
typedef __attribute__((ext_vector_type(4))) float float4v;

__device__ __forceinline__ short f2bf(float f) {
    union { float f; unsigned u; } x; x.f = f;
    unsigned r = (x.u + 0x7fffu + ((x.u >> 16) & 1u)) >> 16;  // RNE
    return (short)r;
}

// async 16B global->LDS (m97 path). LDS dest = wave-uniform base + lane*16.
#define ASYNC16(gp, lp) __builtin_amdgcn_global_load_lds( \
    (__attribute__((address_space(1))) void*)(gp), \
    (__attribute__((address_space(3))) void*)(lp), 16, 0, 0)

// ---------------- setup: parallel dedup'd global list (order irrelevant) ----------------
__global__ void setup_globals(const int* __restrict__ gidx, int* __restrict__ g,
                              int* __restrict__ glist, int* __restrict__ gcount) {
    int t = threadIdx.x;
    for (int i = t; i < SS; i += 256) g[i] = 0;
    if (t == 0) *gcount = 0;
    __syncthreads();
    if (t < NGLOB) {
        int j = gidx[t];
        if (j >= 0 && j < SS) g[j] = 1;
    }
    __syncthreads();
    for (int j = t; j < SS; j += 256) {
        if (g[j]) {
            int p = atomicAdd(gcount, 1);
            glist[p] = j;
        }
    }
}

// ---------------- convert inputs q,k,v (4M ea) + 4 weights (1M ea) fp32 -> bf16 ----------------
__global__ __launch_bounds__(256)
void convert_all(const float* __restrict__ q, const float* __restrict__ k,
                 const float* __restrict__ v,
                 const float* __restrict__ w0, const float* __restrict__ w1,
                 const float* __restrict__ w2, const float* __restrict__ w3,
                 short* __restrict__ abf, short* __restrict__ wbf) {
    int z = blockIdx.y;
    const float* src;
    short* dst;
    size_t n;
    if (z < 3) {
        src = (z == 0) ? q : (z == 1) ? k : v;
        dst = abf + (size_t)z * ((size_t)MM * DMM);
        n = (size_t)MM * DMM;
    } else {
        int y = z - 3;
        src = (y == 0) ? w0 : (y == 1) ? w1 : (y == 2) ? w2 : w3;
        dst = wbf + (size_t)y * ((size_t)DMM * DMM);
        n = (size_t)DMM * DMM;
    }
    size_t i = ((size_t)blockIdx.x * 256 + threadIdx.x) * 8;
    if (i >= n) return;
    float4 a = *(const float4*)(src + i);
    float4 b = *(const float4*)(src + i + 4);
    short8 s;
    s[0]=f2bf(a.x); s[1]=f2bf(a.y); s[2]=f2bf(a.z); s[3]=f2bf(a.w);
    s[4]=f2bf(b.x); s[5]=f2bf(b.y); s[6]=f2bf(b.z); s[7]=f2bf(b.w);
    *(short8*)(dst + i) = s;
}

// ---------------- m97-style MFMA GEMM: C = A * W^T + bias ----------------
// A: [M=4096,K=1024] bf16, W: [N=1024,K] bf16, out fp32 (OBF=0) or bf16 (OBF=1).
// 128x128 tile, BK=32, 256 threads (4 waves, 64x64 quadrant each, 4x4 acc).
// Staging: 4 x global_load_lds(16B) per thread, linear LDS (stride 32 shorts).
// Grid (256, nz): z batches QKV; XCD-panel swizzle (A 1MB panel + W 2MB < 4MB L2).
template<int OBF, int HEADSPLIT>
__global__ __launch_bounds__(256)
void gemm128(const short* __restrict__ Abase, const short* __restrict__ Wbase,
             const float* __restrict__ b0, const float* __restrict__ b1,
             const float* __restrict__ b2,
             void* __restrict__ O0p, void* __restrict__ O1p, void* __restrict__ O2p) {
    __shared__ short As[128 * 32];   // 8 KB
    __shared__ short Ws[128 * 32];   // 8 KB

    int t = threadIdx.x;
    int z = blockIdx.y;
    const short* A    = Abase + (size_t)z * ((size_t)MM * DMM);
    const short* W    = Wbase + (size_t)z * ((size_t)DMM * DMM);
    const float* bias = (z == 0) ? b0 : (z == 1) ? b1 : b2;
    void* outp        = (z == 0) ? O0p : (z == 1) ? O1p : O2p;

    int bid = blockIdx.x;
    int xcd = bid & 7, loc = bid >> 3;    // XCD round-robin
    int nblk = loc & 7, mloc = loc >> 3;  // per-XCD: 4 m-blocks x 8 n-blocks
    int m0 = (xcd * 4 + mloc) * 128;
    int n0 = nblk * 128;

    int lane = t & 63, w = t >> 6;
    int quad = lane >> 4, col = lane & 15;
    int arow0 = (w & 1) * 64;
    int ncol0 = (w >> 1) * 64;

    float4v acc[4][4];
    #pragma unroll
    for (int i = 0; i < 4; i++)
        #pragma unroll
        for (int j = 0; j < 4; j++) acc[i][j] = (float4v){0, 0, 0, 0};

    // staging chunk geometry: chunk = r*256 + t; row = chunk>>2, kchunk = chunk&3
    int row0 = t >> 2;        // r=0 rows 0..63 ; r=1 rows 64..127
    int kc8  = (t & 3) * 8;   // short offset within row

    for (int it = 0; it < 32; it++) {
        int k0 = it * 32;
        ASYNC16(A + (size_t)(m0 + row0) * DMM + k0 + kc8,      &As[t * 8]);
        ASYNC16(A + (size_t)(m0 + 64 + row0) * DMM + k0 + kc8, &As[2048 + t * 8]);
        ASYNC16(W + (size_t)(n0 + row0) * DMM + k0 + kc8,      &Ws[t * 8]);
        ASYNC16(W + (size_t)(n0 + 64 + row0) * DMM + k0 + kc8, &Ws[2048 + t * 8]);
        __syncthreads();   // drains vmcnt (loads -> LDS) + joins waves

        short8 aF[4], bF[4];
        #pragma unroll
        for (int i = 0; i < 4; i++)
            aF[i] = *(short8*)&As[(arow0 + 16 * i + col) * 32 + quad * 8];
        #pragma unroll
        for (int j = 0; j < 4; j++)
            bF[j] = *(short8*)&Ws[(ncol0 + 16 * j + col) * 32 + quad * 8];

        #pragma unroll
        for (int i = 0; i < 4; i++)
            #pragma unroll
            for (int j = 0; j < 4; j++)
                acc[i][j] = __builtin_amdgcn_mfma_f32_16x16x32_bf16(aF[i], bF[j], acc[i][j], 0, 0, 0);
        __syncthreads();   // readers done before next tile overwrites
    }

    #pragma unroll
    for (int i = 0; i < 4; i++) {
        #pragma unroll
        for (int j = 0; j < 4; j++) {
            int n = n0 + ncol0 + 16 * j + col;
            float bn = bias[n];
            #pragma unroll
            for (int r = 0; r < 4; r++) {
                int m = m0 + arow0 + 16 * i + quad * 4 + r;
                float val = acc[i][j][r] + bn;
                size_t idx;
                if (HEADSPLIT) {
                    int b = m >> 11;
                    int s = m & 2047;
                    int h = n >> 6;
                    int hd = n & 63;
                    idx = (((size_t)b * HH + h) * SS + s) * HDD + hd;
                } else {
                    idx = (size_t)m * DMM + n;
                }
                if (OBF) ((short*)outp)[idx] = f2bf(val);
                else     ((float*)outp)[idx] = val;
            }
        }
    }
}

// ---------------- banded MFMA attention (parity-split flash; no-max softmax) ----------------
__global__ __launch_bounds__(256)
void band_attn(const short* __restrict__ qh, const short* __restrict__ kh,
               const short* __restrict__ vh, const int* __restrict__ glist,
               const int* __restrict__ gcount, short* __restrict__ ao) {
    __shared__ short Qs[64 * 72];
    __shared__ short Ks[32 * 72];
    __shared__ short Vt[64 * 40];
    __shared__ short Ps[4 * 16 * 40];
    __shared__ int   gjs[32];

    int t = threadIdx.x;
    int qt = blockIdx.x, h = blockIdx.y, z = blockIdx.z;
    int b = z >> 1, p = z & 1;
    int qq0 = qt * 64;
    int nG = *gcount;

    const short* Qb = qh + ((size_t)(b * HH + h) * SS) * HDD;
    const short* Kb = kh + ((size_t)(b * HH + h) * SS) * HDD;
    const short* Vb = vh + ((size_t)(b * HH + h) * SS) * HDD;

    int row8 = t >> 3;
    int dim8 = (t & 7) * 8;

    #pragma unroll
    for (int rr = 0; rr < 2; rr++) {
        int row = rr * 32 + row8;
        int i = 2 * (qq0 + row) + p;
        short8 qv = *(const short8*)(Qb + (size_t)i * HDD + dim8);
        *(short8*)&Qs[row * 72 + dim8] = qv;
    }
    if (t < 32) gjs[t] = (t < nG) ? glist[t] : -1000000;
    __syncthreads();

    int lane = t & 63, w = t >> 6;
    int quad = lane >> 4, col = lane & 15;

    short8 qf0 = *(short8*)&Qs[(16 * w + col) * 72 + quad * 8];
    short8 qf1 = *(short8*)&Qs[(16 * w + col) * 72 + 32 + quad * 8];

    float4v O0 = {0,0,0,0}, O1 = {0,0,0,0}, O2 = {0,0,0,0}, O3 = {0,0,0,0};
    float lst[4] = {0.f, 0.f, 0.f, 0.f};

    for (int c = 0; c < 19; c++) {
        __syncthreads();
        int ch0 = qq0 - 256 + c * 32;
        int srow;
        if (c < 18) srow = 2 * (ch0 + row8) + p;
        else        srow = (row8 < nG) ? gjs[row8] : 0;
        srow = srow < 0 ? 0 : (srow > SS - 1 ? SS - 1 : srow);
        short8 kv = *(const short8*)(Kb + (size_t)srow * HDD + dim8);
        short8 vv = *(const short8*)(Vb + (size_t)srow * HDD + dim8);
        *(short8*)&Ks[row8 * 72 + dim8] = kv;
        #pragma unroll
        for (int j = 0; j < 8; j++) Vt[(dim8 + j) * 40 + row8] = vv[j];
        __syncthreads();

        short8 kA0 = *(short8*)&Ks[col * 72 + quad * 8];
        short8 kA1 = *(short8*)&Ks[col * 72 + 32 + quad * 8];
        short8 kB0 = *(short8*)&Ks[(16 + col) * 72 + quad * 8];
        short8 kB1 = *(short8*)&Ks[(16 + col) * 72 + 32 + quad * 8];
        float4v sA = {0,0,0,0}, sB = {0,0,0,0};
        sA = __builtin_amdgcn_mfma_f32_16x16x32_bf16(qf0, kA0, sA, 0, 0, 0);
        sA = __builtin_amdgcn_mfma_f32_16x16x32_bf16(qf1, kA1, sA, 0, 0, 0);
        sB = __builtin_amdgcn_mfma_f32_16x16x32_bf16(qf0, kB0, sB, 0, 0, 0);
        sB = __builtin_amdgcn_mfma_f32_16x16x32_bf16(qf1, kB1, sB, 0, 0, 0);

        #pragma unroll
        for (int r = 0; r < 4; r++) {
            int q  = 16 * w + quad * 4 + r;
            int qq = qq0 + q;
            bool vA, vB;
            if (c < 18) {
                int jA = ch0 + col, jB = jA + 16;
                int dA = jA - qq; dA = dA < 0 ? -dA : dA;
                int dB = jB - qq; dB = dB < 0 ? -dB : dB;
                vA = (jA >= 0) && (jA < 1024) && (dA <= 256);
                vB = (jB >= 0) && (jB < 1024) && (dB <= 256);
            } else {
                int i = 2 * qq + p;
                int jA = gjs[col], jB = gjs[col + 16];
                int dA = jA - i, dB = jB - i;
                int aA = dA < 0 ? -dA : dA;
                int aB = dB < 0 ? -dB : dB;
                vA = (jA >= 0) && !((aA <= 512) && ((dA & 1) == 0));
                vB = (jB >= 0) && !((aB <= 512) && ((dB & 1) == 0));
            }
            float pa = vA ? __expf(sA[r] * 0.125f) : 0.f;
            float pb = vB ? __expf(sB[r] * 0.125f) : 0.f;
            lst[r] += pa + pb;
            Ps[(w * 16 + quad * 4 + r) * 40 + col]      = f2bf(pa);
            Ps[(w * 16 + quad * 4 + r) * 40 + col + 16] = f2bf(pb);
        }
        asm volatile("s_waitcnt lgkmcnt(0)" ::: "memory");

        short8 pf  = *(short8*)&Ps[(w * 16 + col) * 40 + quad * 8];
        short8 vf0 = *(short8*)&Vt[(col) * 40 + quad * 8];
        short8 vf1 = *(short8*)&Vt[(16 + col) * 40 + quad * 8];
        short8 vf2 = *(short8*)&Vt[(32 + col) * 40 + quad * 8];
        short8 vf3 = *(short8*)&Vt[(48 + col) * 40 + quad * 8];
        O0 = __builtin_amdgcn_mfma_f32_16x16x32_bf16(pf, vf0, O0, 0, 0, 0);
        O1 = __builtin_amdgcn_mfma_f32_16x16x32_bf16(pf, vf1, O1, 0, 0, 0);
        O2 = __builtin_amdgcn_mfma_f32_16x16x32_bf16(pf, vf2, O2, 0, 0, 0);
        O3 = __builtin_amdgcn_mfma_f32_16x16x32_bf16(pf, vf3, O3, 0, 0, 0);
    }

    #pragma unroll
    for (int r = 0; r < 4; r++) {
        float l = lst[r];
        #pragma unroll
        for (int mk = 1; mk < 16; mk <<= 1) l += __shfl_xor(l, mk);
        float inv = 1.0f / l;
        int q = 16 * w + quad * 4 + r;
        int i = 2 * (qq0 + q) + p;
        short* dst = ao + ((size_t)b * SS + i) * DMM + h * HDD;
        dst[col]      = f2bf(O0[r] * inv);
        dst[col + 16] = f2bf(O1[r] * inv);
        dst[col + 32] = f2bf(O2[r] * inv);
        dst[col + 48] = f2bf(O3[r] * inv);
    }
}

// ---------------- global rows: split-K MFMA partials (no-max softmax) ----------------
__global__ __launch_bounds__(256)
void global_part(const short* __restrict__ qh, const short* __restrict__ kh,
                 const short* __restrict__ vh, const int* __restrict__ glist,
                 const int* __restrict__ gcount,
                 float* __restrict__ pl, float* __restrict__ pO) {
    __shared__ short Qs[32 * 72];
    __shared__ short Ks[2][32 * 72];
    __shared__ short Vt[2][64 * 40];
    __shared__ short Ps[4 * 16 * 40];

    int t = threadIdx.x;
    int s = blockIdx.x, h = blockIdx.y, b = blockIdx.z;
    int nG = *gcount;

    const short* Qb = qh + ((size_t)(b * HH + h) * SS) * HDD;
    const short* Kb = kh + ((size_t)(b * HH + h) * SS) * HDD;
    const short* Vb = vh + ((size_t)(b * HH + h) * SS) * HDD;

    int row8 = t >> 3, dim8 = (t & 7) * 8;
    {
        int cq = row8 < nG ? row8 : 0;
        int src = glist[cq];
        short8 qv = *(const short8*)(Qb + (size_t)src * HDD + dim8);
        *(short8*)&Qs[row8 * 72 + dim8] = qv;
    }
    __syncthreads();

    int lane = t & 63, w = t >> 6;
    int quad = lane >> 4, col = lane & 15;
    int g = w >> 1, qt = w & 1;

    short8 qf0 = *(short8*)&Qs[(qt * 16 + col) * 72 + quad * 8];
    short8 qf1 = *(short8*)&Qs[(qt * 16 + col) * 72 + 32 + quad * 8];

    float4v O0 = {0,0,0,0}, O1 = {0,0,0,0}, O2 = {0,0,0,0}, O3 = {0,0,0,0};
    float lst[4] = {0.f, 0.f, 0.f, 0.f};

    int js0 = s * 256;
    for (int it = 0; it < 4; it++) {
        __syncthreads();
        int r64 = t >> 2, dimb = (t & 3) * 16;
        int j = js0 + it * 64 + r64;
        const short* kp = Kb + (size_t)j * HDD + dimb;
        const short* vp = Vb + (size_t)j * HDD + dimb;
        short8 k0 = *(const short8*)kp, k1 = *(const short8*)(kp + 8);
        short8 v0 = *(const short8*)vp, v1 = *(const short8*)(vp + 8);
        int half = r64 >> 5, r32 = r64 & 31;
        *(short8*)&Ks[half][r32 * 72 + dimb]     = k0;
        *(short8*)&Ks[half][r32 * 72 + dimb + 8] = k1;
        #pragma unroll
        for (int u = 0; u < 8; u++) Vt[half][(dimb + u) * 40 + r32]     = v0[u];
        #pragma unroll
        for (int u = 0; u < 8; u++) Vt[half][(dimb + 8 + u) * 40 + r32] = v1[u];
        __syncthreads();

        short8 kA0 = *(short8*)&Ks[g][col * 72 + quad * 8];
        short8 kA1 = *(short8*)&Ks[g][col * 72 + 32 + quad * 8];
        short8 kB0 = *(short8*)&Ks[g][(16 + col) * 72 + quad * 8];
        short8 kB1 = *(short8*)&Ks[g][(16 + col) * 72 + 32 + quad * 8];
        float4v sA = {0,0,0,0}, sB = {0,0,0,0};
        sA = __builtin_amdgcn_mfma_f32_16x16x32_bf16(qf0, kA0, sA, 0, 0, 0);
        sA = __builtin_amdgcn_mfma_f32_16x16x32_bf16(qf1, kA1, sA, 0, 0, 0);
        sB = __builtin_amdgcn_mfma_f32_16x16x32_bf16(qf0, kB0, sB, 0, 0, 0);
        sB = __builtin_amdgcn_mfma_f32_16x16x32_bf16(qf1, kB1, sB, 0, 0, 0);

        #pragma unroll
        for (int r = 0; r < 4; r++) {
            float pa = __expf(sA[r] * 0.125f);
            float pb = __expf(sB[r] * 0.125f);
            lst[r] += pa + pb;
            Ps[(w * 16 + quad * 4 + r) * 40 + col]      = f2bf(pa);
            Ps[(w * 16 + quad * 4 + r) * 40 + col + 16] = f2bf(pb);
        }
        asm volatile("s_waitcnt lgkmcnt(0)" ::: "memory");

        short8 pf  = *(short8*)&Ps[(w * 16 + col) * 40 + quad * 8];
        short8 vf0 = *(short8*)&Vt[g][(col) * 40 + quad * 8];
        short8 vf1 = *(short8*)&Vt[g][(16 + col) * 40 + quad * 8];
        short8 vf2 = *(short8*)&Vt[g][(32 + col) * 40 + quad * 8];
        short8 vf3 = *(short8*)&Vt[g][(48 + col) * 40 + quad * 8];
        O0 = __builtin_amdgcn_mfma_f32_16x16x32_bf16(pf, vf0, O0, 0, 0, 0);
        O1 = __builtin_amdgcn_mfma_f32_16x16x32_bf16(pf, vf1, O1, 0, 0, 0);
        O2 = __builtin_amdgcn_mfma_f32_16x16x32_bf16(pf, vf2, O2, 0, 0, 0);
        O3 = __builtin_amdgcn_mfma_f32_16x16x32_bf16(pf, vf3, O3, 0, 0, 0);
    }

    int sp = s * 2 + g;
    size_t base = ((size_t)(b * HH + h) * 16 + sp) * 32;
    #pragma unroll
    for (int r = 0; r < 4; r++) {
        float l = lst[r];
        #pragma unroll
        for (int mk = 1; mk < 16; mk <<= 1) l += __shfl_xor(l, mk);
        int q = qt * 16 + quad * 4 + r;
        if (col == 0) pl[base + q] = l;
        float* Od = pO + (base + q) * 64;
        Od[col]      = O0[r];
        Od[col + 16] = O1[r];
        Od[col + 32] = O2[r];
        Od[col + 48] = O3[r];
    }
}

// ---------------- merge 16 partials per (b,h): plain sums ----------------
__global__ __launch_bounds__(256)
void global_merge(const float* __restrict__ pl, const float* __restrict__ pO,
                  const int* __restrict__ glist, const int* __restrict__ gcount,
                  short* __restrict__ ao) {
    int h = blockIdx.x, b = blockIdx.y;
    int t = threadIdx.x;
    int d = t & 63, qg = t >> 6;
    int nG = *gcount;
    size_t bh = ((size_t)(b * HH + h) * 16) * 32;

    for (int q = qg; q < nG; q += 4) {
        float L = 0.f, acc = 0.f;
        #pragma unroll
        for (int sp = 0; sp < 16; sp++) {
            L   += pl[bh + sp * 32 + q];
            acc += pO[(bh + sp * 32 + q) * 64 + d];
        }
        int i = glist[q];
        ao[((size_t)b * SS + i) * DMM + h * HDD + d] = f2bf(acc / L);
    }
}

extern "C" void kernel_launch(void* const* d_in, const int* in_sizes, int n_in,
                              void* d_out, int out_size, void* d_ws, size_t ws_size,
                              hipStream_t stream) {
    const float* q  = (const float*)d_in[0];
    const float* k  = (const float*)d_in[1];
    const float* v  = (const float*)d_in[2];
    const float* Wq = (const float*)d_in[3];
    const float* Wk = (const float*)d_in[4];
    const float* Wv = (const float*)d_in[5];
    const float* Wo = (const float*)d_in[6];
    const float* bq = (const float*)d_in[7];
    const float* bk = (const float*)d_in[8];
    const float* bv = (const float*)d_in[9];
    const float* bo = (const float*)d_in[10];
    const int* gidx = (const int*)d_in[11];
    float* out = (float*)d_out;

    // ws (64.03 MB, == R2-proven footprint):
    //   32KB hdr | qh,kh,vh,ao bf16 8MB ea | wbf 8MB | abf 24MB (aliased by pl+pO after QKV)
    const size_t NE = (size_t)BB * SS * DMM;   // 4M
    const size_t WE = (size_t)DMM * DMM;       // 1M
    int*   g      = (int*)d_ws;
    int*   glist  = g + SS;
    int*   gcount = glist + SS;
    short* qh     = (short*)((char*)d_ws + 32768);
    short* kh     = qh + NE;
    short* vh     = kh + NE;
    short* ao     = vh + NE;
    short* wbf    = ao + NE;
    short* wo     = wbf + 3 * WE;
    short* abf    = wbf + 4 * WE;          // dead after QKV gemm
    float* pl     = (float*)abf;           // alias: written by global_part (later)
    float* pO     = pl + 16384;

    setup_globals<<<1, 256, 0, stream>>>(gidx, g, glist, gcount);

    dim3 gc(2048, 7);
    convert_all<<<gc, 256, 0, stream>>>(q, k, v, Wq, Wk, Wv, Wo, abf, wbf);

    dim3 gq(256, 3);   // batched QKV
    gemm128<1, 1><<<gq, 256, 0, stream>>>(abf, wbf, bq, bk, bv, qh, kh, vh);

    dim3 ga(16, HH, BB * 2);
    band_attn<<<ga, 256, 0, stream>>>(qh, kh, vh, glist, gcount, ao);

    dim3 gp(8, HH, BB);
    global_part<<<gp, 256, 0, stream>>>(qh, kh, vh, glist, gcount, pl, pO);

    dim3 gm(HH, BB);
    global_merge<<<gm, 256, 0, stream>>>(pl, pO, glist, gcount, ao);

    dim3 go(256, 1);
    gemm128<0, 0><<<go, 256, 0, stream>>>(ao, wo, bo, bo, bo, out, out, out);
}

// Round 11
// 244.285 us; speedup vs baseline: 1.0339x; 1.0339x over previous
//
#include <hip/hip_runtime.h>
#include <hip/hip_bf16.h>
#include <math.h>

#define BB 2
#define SS 2048
#define DMM 1024
#define HH 16
#define HDD 64
#define NGLOB 32
#define MM 4096   // B*S

typedef __attribute__((ext_vector_type(8))) short short8;
typedef __attribute__((ext_vector_type(4))) float float4v;

__device__ __forceinline__ short f2bf(float f) {
    union { float f; unsigned u; } x; x.f = f;
    unsigned r = (x.u + 0x7fffu + ((x.u >> 16) & 1u)) >> 16;  // RNE
    return (short)r;
}

// async 16B global->LDS (m97 path). LDS dest = wave-uniform base + lane*16.
#define ASYNC16(gp, lp) __builtin_amdgcn_global_load_lds( \
    (__attribute__((address_space(1))) void*)(gp), \
    (__attribute__((address_space(3))) void*)(lp), 16, 0, 0)

// ---------------- setup: parallel dedup'd global list (order irrelevant) ----------------
__global__ void setup_globals(const int* __restrict__ gidx, int* __restrict__ g,
                              int* __restrict__ glist, int* __restrict__ gcount) {
    int t = threadIdx.x;
    for (int i = t; i < SS; i += 256) g[i] = 0;
    if (t == 0) *gcount = 0;
    __syncthreads();
    if (t < NGLOB) {
        int j = gidx[t];
        if (j >= 0 && j < SS) g[j] = 1;
    }
    __syncthreads();
    for (int j = t; j < SS; j += 256) {
        if (g[j]) {
            int p = atomicAdd(gcount, 1);
            glist[p] = j;
        }
    }
}

// ---------------- convert inputs q,k,v (4M ea) + 4 weights (1M ea) fp32 -> bf16 ----------------
__global__ __launch_bounds__(256)
void convert_all(const float* __restrict__ q, const float* __restrict__ k,
                 const float* __restrict__ v,
                 const float* __restrict__ w0, const float* __restrict__ w1,
                 const float* __restrict__ w2, const float* __restrict__ w3,
                 short* __restrict__ abf, short* __restrict__ wbf) {
    int z = blockIdx.y;
    const float* src;
    short* dst;
    size_t n;
    if (z < 3) {
        src = (z == 0) ? q : (z == 1) ? k : v;
        dst = abf + (size_t)z * ((size_t)MM * DMM);
        n = (size_t)MM * DMM;
    } else {
        int y = z - 3;
        src = (y == 0) ? w0 : (y == 1) ? w1 : (y == 2) ? w2 : w3;
        dst = wbf + (size_t)y * ((size_t)DMM * DMM);
        n = (size_t)DMM * DMM;
    }
    size_t i = ((size_t)blockIdx.x * 256 + threadIdx.x) * 8;
    if (i >= n) return;
    float4 a = *(const float4*)(src + i);
    float4 b = *(const float4*)(src + i + 4);
    short8 s;
    s[0]=f2bf(a.x); s[1]=f2bf(a.y); s[2]=f2bf(a.z); s[3]=f2bf(a.w);
    s[4]=f2bf(b.x); s[5]=f2bf(b.y); s[6]=f2bf(b.z); s[7]=f2bf(b.w);
    *(short8*)(dst + i) = s;
}

// ---------------- m97-style MFMA GEMM, 64x128 tile: C = A * W^T + bias ----------------
// A: [M,K=1024] bf16, W: [N=1024,K] bf16. BK=32, 256 threads (4 waves, 32x64 each).
// Staging: 3 x global_load_lds(16B)/thread; grid (512, nz): 6 blocks/CU batched QKV.
// XCD-panel swizzle: per-XCD A panel 1MB + W 2MB < 4MB L2.
template<int OBF, int HEADSPLIT>
__global__ __launch_bounds__(256)
void gemm64(const short* __restrict__ Abase, const short* __restrict__ Wbase,
            const float* __restrict__ b0, const float* __restrict__ b1,
            const float* __restrict__ b2,
            void* __restrict__ O0p, void* __restrict__ O1p, void* __restrict__ O2p) {
    __shared__ short As[64 * 32];    // 4 KB
    __shared__ short Ws[128 * 32];   // 8 KB

    int t = threadIdx.x;
    int z = blockIdx.y;
    const short* A    = Abase + (size_t)z * ((size_t)MM * DMM);
    const short* W    = Wbase + (size_t)z * ((size_t)DMM * DMM);
    const float* bias = (z == 0) ? b0 : (z == 1) ? b1 : b2;
    void* outp        = (z == 0) ? O0p : (z == 1) ? O1p : O2p;

    int bid = blockIdx.x;
    int xcd = bid & 7, loc = bid >> 3;    // XCD round-robin
    int nblk = loc & 7, mloc = loc >> 3;  // per-XCD: 8 m-blocks x 8 n-blocks
    int m0 = (xcd * 8 + mloc) * 64;
    int n0 = nblk * 128;

    int lane = t & 63, w = t >> 6;
    int quad = lane >> 4, col = lane & 15;
    int arow0 = (w & 1) * 32;
    int ncol0 = (w >> 1) * 64;

    float4v acc[2][4];
    #pragma unroll
    for (int i = 0; i < 2; i++)
        #pragma unroll
        for (int j = 0; j < 4; j++) acc[i][j] = (float4v){0, 0, 0, 0};

    // staging: chunk ch -> row=ch>>2, kcol=(ch&3)*8 ; A: ch=t ; W: ch=t, 256+t
    int rowA = t >> 2,  kcA = (t & 3) * 8;

    for (int it = 0; it < 32; it++) {
        int k0 = it * 32;
        ASYNC16(A + (size_t)(m0 + rowA) * DMM + k0 + kcA,      &As[t * 8]);
        ASYNC16(W + (size_t)(n0 + rowA) * DMM + k0 + kcA,      &Ws[t * 8]);
        ASYNC16(W + (size_t)(n0 + 64 + rowA) * DMM + k0 + kcA, &Ws[2048 + t * 8]);
        __syncthreads();   // drains vmcnt + joins waves

        short8 aF[2], bF[4];
        #pragma unroll
        for (int i = 0; i < 2; i++)
            aF[i] = *(short8*)&As[(arow0 + 16 * i + col) * 32 + quad * 8];
        #pragma unroll
        for (int j = 0; j < 4; j++)
            bF[j] = *(short8*)&Ws[(ncol0 + 16 * j + col) * 32 + quad * 8];

        #pragma unroll
        for (int i = 0; i < 2; i++)
            #pragma unroll
            for (int j = 0; j < 4; j++)
                acc[i][j] = __builtin_amdgcn_mfma_f32_16x16x32_bf16(aF[i], bF[j], acc[i][j], 0, 0, 0);
        __syncthreads();   // readers done before next tile overwrites
    }

    #pragma unroll
    for (int i = 0; i < 2; i++) {
        #pragma unroll
        for (int j = 0; j < 4; j++) {
            int n = n0 + ncol0 + 16 * j + col;
            float bn = bias[n];
            #pragma unroll
            for (int r = 0; r < 4; r++) {
                int m = m0 + arow0 + 16 * i + quad * 4 + r;
                float val = acc[i][j][r] + bn;
                size_t idx;
                if (HEADSPLIT) {
                    int b = m >> 11;
                    int s = m & 2047;
                    int h = n >> 6;
                    int hd = n & 63;
                    idx = (((size_t)b * HH + h) * SS + s) * HDD + hd;
                } else {
                    idx = (size_t)m * DMM + n;
                }
                if (OBF) ((short*)outp)[idx] = f2bf(val);
                else     ((float*)outp)[idx] = val;
            }
        }
    }
}

// ---------------- banded MFMA attention (parity-split flash; no-max softmax) ----------------
__global__ __launch_bounds__(256)
void band_attn(const short* __restrict__ qh, const short* __restrict__ kh,
               const short* __restrict__ vh, const int* __restrict__ glist,
               const int* __restrict__ gcount, short* __restrict__ ao) {
    __shared__ short Qs[64 * 72];
    __shared__ short Ks[32 * 72];
    __shared__ short Vt[64 * 40];
    __shared__ short Ps[4 * 16 * 40];
    __shared__ int   gjs[32];

    int t = threadIdx.x;
    int qt = blockIdx.x, h = blockIdx.y, z = blockIdx.z;
    int b = z >> 1, p = z & 1;
    int qq0 = qt * 64;
    int nG = *gcount;

    const short* Qb = qh + ((size_t)(b * HH + h) * SS) * HDD;
    const short* Kb = kh + ((size_t)(b * HH + h) * SS) * HDD;
    const short* Vb = vh + ((size_t)(b * HH + h) * SS) * HDD;

    int row8 = t >> 3;
    int dim8 = (t & 7) * 8;

    #pragma unroll
    for (int rr = 0; rr < 2; rr++) {
        int row = rr * 32 + row8;
        int i = 2 * (qq0 + row) + p;
        short8 qv = *(const short8*)(Qb + (size_t)i * HDD + dim8);
        *(short8*)&Qs[row * 72 + dim8] = qv;
    }
    if (t < 32) gjs[t] = (t < nG) ? glist[t] : -1000000;
    __syncthreads();

    int lane = t & 63, w = t >> 6;
    int quad = lane >> 4, col = lane & 15;

    short8 qf0 = *(short8*)&Qs[(16 * w + col) * 72 + quad * 8];
    short8 qf1 = *(short8*)&Qs[(16 * w + col) * 72 + 32 + quad * 8];

    float4v O0 = {0,0,0,0}, O1 = {0,0,0,0}, O2 = {0,0,0,0}, O3 = {0,0,0,0};
    float lst[4] = {0.f, 0.f, 0.f, 0.f};

    for (int c = 0; c < 19; c++) {
        __syncthreads();
        int ch0 = qq0 - 256 + c * 32;
        int srow;
        if (c < 18) srow = 2 * (ch0 + row8) + p;
        else        srow = (row8 < nG) ? gjs[row8] : 0;
        srow = srow < 0 ? 0 : (srow > SS - 1 ? SS - 1 : srow);
        short8 kv = *(const short8*)(Kb + (size_t)srow * HDD + dim8);
        short8 vv = *(const short8*)(Vb + (size_t)srow * HDD + dim8);
        *(short8*)&Ks[row8 * 72 + dim8] = kv;
        #pragma unroll
        for (int j = 0; j < 8; j++) Vt[(dim8 + j) * 40 + row8] = vv[j];
        __syncthreads();

        short8 kA0 = *(short8*)&Ks[col * 72 + quad * 8];
        short8 kA1 = *(short8*)&Ks[col * 72 + 32 + quad * 8];
        short8 kB0 = *(short8*)&Ks[(16 + col) * 72 + quad * 8];
        short8 kB1 = *(short8*)&Ks[(16 + col) * 72 + 32 + quad * 8];
        float4v sA = {0,0,0,0}, sB = {0,0,0,0};
        sA = __builtin_amdgcn_mfma_f32_16x16x32_bf16(qf0, kA0, sA, 0, 0, 0);
        sA = __builtin_amdgcn_mfma_f32_16x16x32_bf16(qf1, kA1, sA, 0, 0, 0);
        sB = __builtin_amdgcn_mfma_f32_16x16x32_bf16(qf0, kB0, sB, 0, 0, 0);
        sB = __builtin_amdgcn_mfma_f32_16x16x32_bf16(qf1, kB1, sB, 0, 0, 0);

        #pragma unroll
        for (int r = 0; r < 4; r++) {
            int q  = 16 * w + quad * 4 + r;
            int qq = qq0 + q;
            bool vA, vB;
            if (c < 18) {
                int jA = ch0 + col, jB = jA + 16;
                int dA = jA - qq; dA = dA < 0 ? -dA : dA;
                int dB = jB - qq; dB = dB < 0 ? -dB : dB;
                vA = (jA >= 0) && (jA < 1024) && (dA <= 256);
                vB = (jB >= 0) && (jB < 1024) && (dB <= 256);
            } else {
                int i = 2 * qq + p;
                int jA = gjs[col], jB = gjs[col + 16];
                int dA = jA - i, dB = jB - i;
                int aA = dA < 0 ? -dA : dA;
                int aB = dB < 0 ? -dB : dB;
                vA = (jA >= 0) && !((aA <= 512) && ((dA & 1) == 0));
                vB = (jB >= 0) && !((aB <= 512) && ((dB & 1) == 0));
            }
            float pa = vA ? __expf(sA[r] * 0.125f) : 0.f;
            float pb = vB ? __expf(sB[r] * 0.125f) : 0.f;
            lst[r] += pa + pb;
            Ps[(w * 16 + quad * 4 + r) * 40 + col]      = f2bf(pa);
            Ps[(w * 16 + quad * 4 + r) * 40 + col + 16] = f2bf(pb);
        }
        asm volatile("s_waitcnt lgkmcnt(0)" ::: "memory");

        short8 pf  = *(short8*)&Ps[(w * 16 + col) * 40 + quad * 8];
        short8 vf0 = *(short8*)&Vt[(col) * 40 + quad * 8];
        short8 vf1 = *(short8*)&Vt[(16 + col) * 40 + quad * 8];
        short8 vf2 = *(short8*)&Vt[(32 + col) * 40 + quad * 8];
        short8 vf3 = *(short8*)&Vt[(48 + col) * 40 + quad * 8];
        O0 = __builtin_amdgcn_mfma_f32_16x16x32_bf16(pf, vf0, O0, 0, 0, 0);
        O1 = __builtin_amdgcn_mfma_f32_16x16x32_bf16(pf, vf1, O1, 0, 0, 0);
        O2 = __builtin_amdgcn_mfma_f32_16x16x32_bf16(pf, vf2, O2, 0, 0, 0);
        O3 = __builtin_amdgcn_mfma_f32_16x16x32_bf16(pf, vf3, O3, 0, 0, 0);
    }

    #pragma unroll
    for (int r = 0; r < 4; r++) {
        float l = lst[r];
        #pragma unroll
        for (int mk = 1; mk < 16; mk <<= 1) l += __shfl_xor(l, mk);
        float inv = 1.0f / l;
        int q = 16 * w + quad * 4 + r;
        int i = 2 * (qq0 + q) + p;
        short* dst = ao + ((size_t)b * SS + i) * DMM + h * HDD;
        dst[col]      = f2bf(O0[r] * inv);
        dst[col + 16] = f2bf(O1[r] * inv);
        dst[col + 32] = f2bf(O2[r] * inv);
        dst[col + 48] = f2bf(O3[r] * inv);
    }
}

// ---------------- global rows: split-K MFMA partials (no-max softmax) ----------------
__global__ __launch_bounds__(256)
void global_part(const short* __restrict__ qh, const short* __restrict__ kh,
                 const short* __restrict__ vh, const int* __restrict__ glist,
                 const int* __restrict__ gcount,
                 float* __restrict__ pl, float* __restrict__ pO) {
    __shared__ short Qs[32 * 72];
    __shared__ short Ks[2][32 * 72];
    __shared__ short Vt[2][64 * 40];
    __shared__ short Ps[4 * 16 * 40];

    int t = threadIdx.x;
    int s = blockIdx.x, h = blockIdx.y, b = blockIdx.z;
    int nG = *gcount;

    const short* Qb = qh + ((size_t)(b * HH + h) * SS) * HDD;
    const short* Kb = kh + ((size_t)(b * HH + h) * SS) * HDD;
    const short* Vb = vh + ((size_t)(b * HH + h) * SS) * HDD;

    int row8 = t >> 3, dim8 = (t & 7) * 8;
    {
        int cq = row8 < nG ? row8 : 0;
        int src = glist[cq];
        short8 qv = *(const short8*)(Qb + (size_t)src * HDD + dim8);
        *(short8*)&Qs[row8 * 72 + dim8] = qv;
    }
    __syncthreads();

    int lane = t & 63, w = t >> 6;
    int quad = lane >> 4, col = lane & 15;
    int g = w >> 1, qt = w & 1;

    short8 qf0 = *(short8*)&Qs[(qt * 16 + col) * 72 + quad * 8];
    short8 qf1 = *(short8*)&Qs[(qt * 16 + col) * 72 + 32 + quad * 8];

    float4v O0 = {0,0,0,0}, O1 = {0,0,0,0}, O2 = {0,0,0,0}, O3 = {0,0,0,0};
    float lst[4] = {0.f, 0.f, 0.f, 0.f};

    int js0 = s * 256;
    for (int it = 0; it < 4; it++) {
        __syncthreads();
        int r64 = t >> 2, dimb = (t & 3) * 16;
        int j = js0 + it * 64 + r64;
        const short* kp = Kb + (size_t)j * HDD + dimb;
        const short* vp = Vb + (size_t)j * HDD + dimb;
        short8 k0 = *(const short8*)kp, k1 = *(const short8*)(kp + 8);
        short8 v0 = *(const short8*)vp, v1 = *(const short8*)(vp + 8);
        int half = r64 >> 5, r32 = r64 & 31;
        *(short8*)&Ks[half][r32 * 72 + dimb]     = k0;
        *(short8*)&Ks[half][r32 * 72 + dimb + 8] = k1;
        #pragma unroll
        for (int u = 0; u < 8; u++) Vt[half][(dimb + u) * 40 + r32]     = v0[u];
        #pragma unroll
        for (int u = 0; u < 8; u++) Vt[half][(dimb + 8 + u) * 40 + r32] = v1[u];
        __syncthreads();

        short8 kA0 = *(short8*)&Ks[g][col * 72 + quad * 8];
        short8 kA1 = *(short8*)&Ks[g][col * 72 + 32 + quad * 8];
        short8 kB0 = *(short8*)&Ks[g][(16 + col) * 72 + quad * 8];
        short8 kB1 = *(short8*)&Ks[g][(16 + col) * 72 + 32 + quad * 8];
        float4v sA = {0,0,0,0}, sB = {0,0,0,0};
        sA = __builtin_amdgcn_mfma_f32_16x16x32_bf16(qf0, kA0, sA, 0, 0, 0);
        sA = __builtin_amdgcn_mfma_f32_16x16x32_bf16(qf1, kA1, sA, 0, 0, 0);
        sB = __builtin_amdgcn_mfma_f32_16x16x32_bf16(qf0, kB0, sB, 0, 0, 0);
        sB = __builtin_amdgcn_mfma_f32_16x16x32_bf16(qf1, kB1, sB, 0, 0, 0);

        #pragma unroll
        for (int r = 0; r < 4; r++) {
            float pa = __expf(sA[r] * 0.125f);
            float pb = __expf(sB[r] * 0.125f);
            lst[r] += pa + pb;
            Ps[(w * 16 + quad * 4 + r) * 40 + col]      = f2bf(pa);
            Ps[(w * 16 + quad * 4 + r) * 40 + col + 16] = f2bf(pb);
        }
        asm volatile("s_waitcnt lgkmcnt(0)" ::: "memory");

        short8 pf  = *(short8*)&Ps[(w * 16 + col) * 40 + quad * 8];
        short8 vf0 = *(short8*)&Vt[g][(col) * 40 + quad * 8];
        short8 vf1 = *(short8*)&Vt[g][(16 + col) * 40 + quad * 8];
        short8 vf2 = *(short8*)&Vt[g][(32 + col) * 40 + quad * 8];
        short8 vf3 = *(short8*)&Vt[g][(48 + col) * 40 + quad * 8];
        O0 = __builtin_amdgcn_mfma_f32_16x16x32_bf16(pf, vf0, O0, 0, 0, 0);
        O1 = __builtin_amdgcn_mfma_f32_16x16x32_bf16(pf, vf1, O1, 0, 0, 0);
        O2 = __builtin_amdgcn_mfma_f32_16x16x32_bf16(pf, vf2, O2, 0, 0, 0);
        O3 = __builtin_amdgcn_mfma_f32_16x16x32_bf16(pf, vf3, O3, 0, 0, 0);
    }

    int sp = s * 2 + g;
    size_t base = ((size_t)(b * HH + h) * 16 + sp) * 32;
    #pragma unroll
    for (int r = 0; r < 4; r++) {
        float l = lst[r];
        #pragma unroll
        for (int mk = 1; mk < 16; mk <<= 1) l += __shfl_xor(l, mk);
        int q = qt * 16 + quad * 4 + r;
        if (col == 0) pl[base + q] = l;
        float* Od = pO + (base + q) * 64;
        Od[col]      = O0[r];
        Od[col + 16] = O1[r];
        Od[col + 32] = O2[r];
        Od[col + 48] = O3[r];
    }
}

// ---------------- merge 16 partials per (b,h): plain sums ----------------
__global__ __launch_bounds__(256)
void global_merge(const float* __restrict__ pl, const float* __restrict__ pO,
                  const int* __restrict__ glist, const int* __restrict__ gcount,
                  short* __restrict__ ao) {
    int h = blockIdx.x, b = blockIdx.y;
    int t = threadIdx.x;
    int d = t & 63, qg = t >> 6;
    int nG = *gcount;
    size_t bh = ((size_t)(b * HH + h) * 16) * 32;

    for (int q = qg; q < nG; q += 4) {
        float L = 0.f, acc = 0.f;
        #pragma unroll
        for (int sp = 0; sp < 16; sp++) {
            L   += pl[bh + sp * 32 + q];
            acc += pO[(bh + sp * 32 + q) * 64 + d];
        }
        int i = glist[q];
        ao[((size_t)b * SS + i) * DMM + h * HDD + d] = f2bf(acc / L);
    }
}

extern "C" void kernel_launch(void* const* d_in, const int* in_sizes, int n_in,
                              void* d_out, int out_size, void* d_ws, size_t ws_size,
                              hipStream_t stream) {
    const float* q  = (const float*)d_in[0];
    const float* k  = (const float*)d_in[1];
    const float* v  = (const float*)d_in[2];
    const float* Wq = (const float*)d_in[3];
    const float* Wk = (const float*)d_in[4];
    const float* Wv = (const float*)d_in[5];
    const float* Wo = (const float*)d_in[6];
    const float* bq = (const float*)d_in[7];
    const float* bk = (const float*)d_in[8];
    const float* bv = (const float*)d_in[9];
    const float* bo = (const float*)d_in[10];
    const int* gidx = (const int*)d_in[11];
    float* out = (float*)d_out;

    // ws (64.03 MB): 32KB hdr | qh,kh,vh,ao bf16 8MB ea | wbf 8MB | abf 24MB (aliased by pl+pO)
    const size_t NE = (size_t)BB * SS * DMM;   // 4M
    const size_t WE = (size_t)DMM * DMM;       // 1M
    int*   g      = (int*)d_ws;
    int*   glist  = g + SS;
    int*   gcount = glist + SS;
    short* qh     = (short*)((char*)d_ws + 32768);
    short* kh     = qh + NE;
    short* vh     = kh + NE;
    short* ao     = vh + NE;
    short* wbf    = ao + NE;
    short* wo     = wbf + 3 * WE;
    short* abf    = wbf + 4 * WE;          // dead after QKV gemm
    float* pl     = (float*)abf;           // alias: written by global_part (later)
    float* pO     = pl + 16384;

    setup_globals<<<1, 256, 0, stream>>>(gidx, g, glist, gcount);

    dim3 gc(2048, 7);
    convert_all<<<gc, 256, 0, stream>>>(q, k, v, Wq, Wk, Wv, Wo, abf, wbf);

    dim3 gq(512, 3);   // batched QKV, 64x128 tiles: 1536 blocks = 6/CU
    gemm64<1, 1><<<gq, 256, 0, stream>>>(abf, wbf, bq, bk, bv, qh, kh, vh);

    dim3 ga(16, HH, BB * 2);
    band_attn<<<ga, 256, 0, stream>>>(qh, kh, vh, glist, gcount, ao);

    dim3 gp(8, HH, BB);
    global_part<<<gp, 256, 0, stream>>>(qh, kh, vh, glist, gcount, pl, pO);

    dim3 gm(HH, BB);
    global_merge<<<gm, 256, 0, stream>>>(pl, pO, glist, gcount, ao);

    dim3 go(512, 1);   // Wo: 512 blocks = 2/CU
    gemm64<0, 0><<<go, 256, 0, stream>>>(ao, wo, bo, bo, bo, out, out, out);
}

// Round 12
// 231.560 us; speedup vs baseline: 1.0907x; 1.0550x over previous
//
#include <hip/hip_runtime.h>
#include <hip/hip_bf16.h>
#include <math.h>

#define BB 2
#define SS 2048
#define DMM 1024
#define HH 16
#define HDD 64
#define NGLOB 32
#define MM 4096   // B*S
#define SCALE2 0.18033688f   // 0.125 * log2(e): exp(s/8) == exp2(s*SCALE2)

typedef __attribute__((ext_vector_type(8))) short short8;
typedef __attribute__((ext_vector_type(4))) float float4v;

__device__ __forceinline__ short f2bf(float f) {
    union { float f; unsigned u; } x; x.f = f;
    unsigned r = (x.u + 0x7fffu + ((x.u >> 16) & 1u)) >> 16;  // RNE
    return (short)r;
}

// async 16B global->LDS (m97 path). LDS dest = wave-uniform base + lane*16.
#define ASYNC16(gp, lp) __builtin_amdgcn_global_load_lds( \
    (__attribute__((address_space(1))) void*)(gp), \
    (__attribute__((address_space(3))) void*)(lp), 16, 0, 0)

// Vt slot swizzle: key-chunk XORed with dim-derived tag -> breaks the
// dim*stride==0 (mod 32 banks) collapse on transpose stores (16-way -> 4-way).
#define VSL(dim, key) ((dim) * 40 + (((((key) >> 3) ^ (((dim) >> 3) & 3)) << 3) | ((key) & 7)))

// ---------------- setup: parallel dedup'd global list (order irrelevant) ----------------
__global__ void setup_globals(const int* __restrict__ gidx, int* __restrict__ g,
                              int* __restrict__ glist, int* __restrict__ gcount) {
    int t = threadIdx.x;
    for (int i = t; i < SS; i += 256) g[i] = 0;
    if (t == 0) *gcount = 0;
    __syncthreads();
    if (t < NGLOB) {
        int j = gidx[t];
        if (j >= 0 && j < SS) g[j] = 1;
    }
    __syncthreads();
    for (int j = t; j < SS; j += 256) {
        if (g[j]) {
            int p = atomicAdd(gcount, 1);
            glist[p] = j;
        }
    }
}

// ---------------- convert inputs q,k,v (4M ea) + 4 weights (1M ea) fp32 -> bf16 ----------------
__global__ __launch_bounds__(256)
void convert_all(const float* __restrict__ q, const float* __restrict__ k,
                 const float* __restrict__ v,
                 const float* __restrict__ w0, const float* __restrict__ w1,
                 const float* __restrict__ w2, const float* __restrict__ w3,
                 short* __restrict__ abf, short* __restrict__ wbf) {
    int z = blockIdx.y;
    const float* src;
    short* dst;
    size_t n;
    if (z < 3) {
        src = (z == 0) ? q : (z == 1) ? k : v;
        dst = abf + (size_t)z * ((size_t)MM * DMM);
        n = (size_t)MM * DMM;
    } else {
        int y = z - 3;
        src = (y == 0) ? w0 : (y == 1) ? w1 : (y == 2) ? w2 : w3;
        dst = wbf + (size_t)y * ((size_t)DMM * DMM);
        n = (size_t)DMM * DMM;
    }
    size_t i = ((size_t)blockIdx.x * 256 + threadIdx.x) * 8;
    if (i >= n) return;
    float4 a = *(const float4*)(src + i);
    float4 b = *(const float4*)(src + i + 4);
    short8 s;
    s[0]=f2bf(a.x); s[1]=f2bf(a.y); s[2]=f2bf(a.z); s[3]=f2bf(a.w);
    s[4]=f2bf(b.x); s[5]=f2bf(b.y); s[6]=f2bf(b.z); s[7]=f2bf(b.w);
    *(short8*)(dst + i) = s;
}

// ---------------- m97-style MFMA GEMM, 64x128 tile (validated R11) ----------------
template<int OBF, int HEADSPLIT>
__global__ __launch_bounds__(256)
void gemm64(const short* __restrict__ Abase, const short* __restrict__ Wbase,
            const float* __restrict__ b0, const float* __restrict__ b1,
            const float* __restrict__ b2,
            void* __restrict__ O0p, void* __restrict__ O1p, void* __restrict__ O2p) {
    __shared__ short As[64 * 32];    // 4 KB
    __shared__ short Ws[128 * 32];   // 8 KB

    int t = threadIdx.x;
    int z = blockIdx.y;
    const short* A    = Abase + (size_t)z * ((size_t)MM * DMM);
    const short* W    = Wbase + (size_t)z * ((size_t)DMM * DMM);
    const float* bias = (z == 0) ? b0 : (z == 1) ? b1 : b2;
    void* outp        = (z == 0) ? O0p : (z == 1) ? O1p : O2p;

    int bid = blockIdx.x;
    int xcd = bid & 7, loc = bid >> 3;    // XCD round-robin
    int nblk = loc & 7, mloc = loc >> 3;  // per-XCD: 8 m-blocks x 8 n-blocks
    int m0 = (xcd * 8 + mloc) * 64;
    int n0 = nblk * 128;

    int lane = t & 63, w = t >> 6;
    int quad = lane >> 4, col = lane & 15;
    int arow0 = (w & 1) * 32;
    int ncol0 = (w >> 1) * 64;

    float4v acc[2][4];
    #pragma unroll
    for (int i = 0; i < 2; i++)
        #pragma unroll
        for (int j = 0; j < 4; j++) acc[i][j] = (float4v){0, 0, 0, 0};

    int rowA = t >> 2,  kcA = (t & 3) * 8;

    for (int it = 0; it < 32; it++) {
        int k0 = it * 32;
        ASYNC16(A + (size_t)(m0 + rowA) * DMM + k0 + kcA,      &As[t * 8]);
        ASYNC16(W + (size_t)(n0 + rowA) * DMM + k0 + kcA,      &Ws[t * 8]);
        ASYNC16(W + (size_t)(n0 + 64 + rowA) * DMM + k0 + kcA, &Ws[2048 + t * 8]);
        __syncthreads();

        short8 aF[2], bF[4];
        #pragma unroll
        for (int i = 0; i < 2; i++)
            aF[i] = *(short8*)&As[(arow0 + 16 * i + col) * 32 + quad * 8];
        #pragma unroll
        for (int j = 0; j < 4; j++)
            bF[j] = *(short8*)&Ws[(ncol0 + 16 * j + col) * 32 + quad * 8];

        #pragma unroll
        for (int i = 0; i < 2; i++)
            #pragma unroll
            for (int j = 0; j < 4; j++)
                acc[i][j] = __builtin_amdgcn_mfma_f32_16x16x32_bf16(aF[i], bF[j], acc[i][j], 0, 0, 0);
        __syncthreads();
    }

    #pragma unroll
    for (int i = 0; i < 2; i++) {
        #pragma unroll
        for (int j = 0; j < 4; j++) {
            int n = n0 + ncol0 + 16 * j + col;
            float bn = bias[n];
            #pragma unroll
            for (int r = 0; r < 4; r++) {
                int m = m0 + arow0 + 16 * i + quad * 4 + r;
                float val = acc[i][j][r] + bn;
                size_t idx;
                if (HEADSPLIT) {
                    int b = m >> 11;
                    int s = m & 2047;
                    int h = n >> 6;
                    int hd = n & 63;
                    idx = (((size_t)b * HH + h) * SS + s) * HDD + hd;
                } else {
                    idx = (size_t)m * DMM + n;
                }
                if (OBF) ((short*)outp)[idx] = f2bf(val);
                else     ((float*)outp)[idx] = val;
            }
        }
    }
}

// ---------------- banded MFMA attention (XCD-local, swizzled Vt, interval mask) ----------------
// 1D grid 1024: all 16 q-tiles of a (b,h,parity) group land on one XCD (L2 reuse).
__global__ __launch_bounds__(256)
void band_attn(const short* __restrict__ qh, const short* __restrict__ kh,
               const short* __restrict__ vh, const int* __restrict__ glist,
               const int* __restrict__ gcount, short* __restrict__ ao) {
    __shared__ short Qs[64 * 72];
    __shared__ short Ks[32 * 72];
    __shared__ short Vt[64 * 40];
    __shared__ short Ps[4 * 16 * 40];
    __shared__ int   gjs[32];

    int t = threadIdx.x;
    int bid = blockIdx.x;
    int xcd = bid & 7, idx = bid >> 3;
    int gl  = idx >> 4;             // 0..7: group slot within XCD
    int qt  = idx & 15;             // q-tile
    int gid = xcd * 8 + gl;         // 0..63 -> (z,h)
    int z   = gid >> 4;
    int h   = gid & 15;
    int b = z >> 1, p = z & 1;
    int qq0 = qt * 64;
    int nG = *gcount;

    const short* Qb = qh + ((size_t)(b * HH + h) * SS) * HDD;
    const short* Kb = kh + ((size_t)(b * HH + h) * SS) * HDD;
    const short* Vb = vh + ((size_t)(b * HH + h) * SS) * HDD;

    int row8 = t >> 3;
    int dim8 = (t & 7) * 8;

    #pragma unroll
    for (int rr = 0; rr < 2; rr++) {
        int row = rr * 32 + row8;
        int i = 2 * (qq0 + row) + p;
        short8 qv = *(const short8*)(Qb + (size_t)i * HDD + dim8);
        *(short8*)&Qs[row * 72 + dim8] = qv;
    }
    if (t < 32) gjs[t] = (t < nG) ? glist[t] : -1000000;
    __syncthreads();

    int lane = t & 63, w = t >> 6;
    int quad = lane >> 4, col = lane & 15;

    short8 qf0 = *(short8*)&Qs[(16 * w + col) * 72 + quad * 8];
    short8 qf1 = *(short8*)&Qs[(16 * w + col) * 72 + 32 + quad * 8];

    float4v O0 = {0,0,0,0}, O1 = {0,0,0,0}, O2 = {0,0,0,0}, O3 = {0,0,0,0};
    float lst[4] = {0.f, 0.f, 0.f, 0.f};

    for (int c = 0; c < 19; c++) {
        __syncthreads();
        int ch0 = qq0 - 256 + c * 32;
        int srow;
        if (c < 18) srow = 2 * (ch0 + row8) + p;
        else        srow = (row8 < nG) ? gjs[row8] : 0;
        srow = srow < 0 ? 0 : (srow > SS - 1 ? SS - 1 : srow);
        short8 kv = *(const short8*)(Kb + (size_t)srow * HDD + dim8);
        short8 vv = *(const short8*)(Vb + (size_t)srow * HDD + dim8);
        *(short8*)&Ks[row8 * 72 + dim8] = kv;
        #pragma unroll
        for (int j = 0; j < 8; j++) {
            int d = dim8 + j;
            Vt[VSL(d, row8)] = vv[j];
        }
        __syncthreads();

        short8 kA0 = *(short8*)&Ks[col * 72 + quad * 8];
        short8 kA1 = *(short8*)&Ks[col * 72 + 32 + quad * 8];
        short8 kB0 = *(short8*)&Ks[(16 + col) * 72 + quad * 8];
        short8 kB1 = *(short8*)&Ks[(16 + col) * 72 + 32 + quad * 8];
        float4v sA = {0,0,0,0}, sB = {0,0,0,0};
        sA = __builtin_amdgcn_mfma_f32_16x16x32_bf16(qf0, kA0, sA, 0, 0, 0);
        sA = __builtin_amdgcn_mfma_f32_16x16x32_bf16(qf1, kA1, sA, 0, 0, 0);
        sB = __builtin_amdgcn_mfma_f32_16x16x32_bf16(qf0, kB0, sB, 0, 0, 0);
        sB = __builtin_amdgcn_mfma_f32_16x16x32_bf16(qf1, kB1, sB, 0, 0, 0);

        if (c < 18) {
            int nlo = -ch0;            // col >= nlo  (jA >= 0)
            int nhi = 1023 - ch0;      // col <= nhi  (jA < 1024)
            #pragma unroll
            for (int r = 0; r < 4; r++) {
                int qq = qq0 + 16 * w + quad * 4 + r;
                int u  = qq - ch0;
                int lo = max(u - 256, nlo);
                int hi = min(u + 256, nhi);
                bool vA = (col >= lo) && (col <= hi);
                bool vB = (col + 16 >= lo) && (col + 16 <= hi);
                float pa = vA ? exp2f(sA[r] * SCALE2) : 0.f;
                float pb = vB ? exp2f(sB[r] * SCALE2) : 0.f;
                lst[r] += pa + pb;
                Ps[(w * 16 + quad * 4 + r) * 40 + col]      = f2bf(pa);
                Ps[(w * 16 + quad * 4 + r) * 40 + col + 16] = f2bf(pb);
            }
        } else {
            #pragma unroll
            for (int r = 0; r < 4; r++) {
                int qq = qq0 + 16 * w + quad * 4 + r;
                int i = 2 * qq + p;
                int jA = gjs[col], jB = gjs[col + 16];
                int dA = jA - i, dB = jB - i;
                int aA = dA < 0 ? -dA : dA;
                int aB = dB < 0 ? -dB : dB;
                bool vA = (jA >= 0) && !((aA <= 512) && ((dA & 1) == 0));
                bool vB = (jB >= 0) && !((aB <= 512) && ((dB & 1) == 0));
                float pa = vA ? exp2f(sA[r] * SCALE2) : 0.f;
                float pb = vB ? exp2f(sB[r] * SCALE2) : 0.f;
                lst[r] += pa + pb;
                Ps[(w * 16 + quad * 4 + r) * 40 + col]      = f2bf(pa);
                Ps[(w * 16 + quad * 4 + r) * 40 + col + 16] = f2bf(pb);
            }
        }
        asm volatile("s_waitcnt lgkmcnt(0)" ::: "memory");

        short8 pf  = *(short8*)&Ps[(w * 16 + col) * 40 + quad * 8];
        short8 vf0 = *(short8*)&Vt[(col) * 40 + ((quad ^ ((col >> 3) & 3)) << 3)];
        short8 vf1 = *(short8*)&Vt[(16 + col) * 40 + ((quad ^ (((16 + col) >> 3) & 3)) << 3)];
        short8 vf2 = *(short8*)&Vt[(32 + col) * 40 + ((quad ^ (((32 + col) >> 3) & 3)) << 3)];
        short8 vf3 = *(short8*)&Vt[(48 + col) * 40 + ((quad ^ (((48 + col) >> 3) & 3)) << 3)];
        O0 = __builtin_amdgcn_mfma_f32_16x16x32_bf16(pf, vf0, O0, 0, 0, 0);
        O1 = __builtin_amdgcn_mfma_f32_16x16x32_bf16(pf, vf1, O1, 0, 0, 0);
        O2 = __builtin_amdgcn_mfma_f32_16x16x32_bf16(pf, vf2, O2, 0, 0, 0);
        O3 = __builtin_amdgcn_mfma_f32_16x16x32_bf16(pf, vf3, O3, 0, 0, 0);
    }

    #pragma unroll
    for (int r = 0; r < 4; r++) {
        float l = lst[r];
        #pragma unroll
        for (int mk = 1; mk < 16; mk <<= 1) l += __shfl_xor(l, mk);
        float inv = 1.0f / l;
        int q = 16 * w + quad * 4 + r;
        int i = 2 * (qq0 + q) + p;
        short* dst = ao + ((size_t)b * SS + i) * DMM + h * HDD;
        dst[col]      = f2bf(O0[r] * inv);
        dst[col + 16] = f2bf(O1[r] * inv);
        dst[col + 32] = f2bf(O2[r] * inv);
        dst[col + 48] = f2bf(O3[r] * inv);
    }
}

// ---------------- global rows: split-K MFMA partials (no-max softmax) ----------------
__global__ __launch_bounds__(256)
void global_part(const short* __restrict__ qh, const short* __restrict__ kh,
                 const short* __restrict__ vh, const int* __restrict__ glist,
                 const int* __restrict__ gcount,
                 float* __restrict__ pl, float* __restrict__ pO) {
    __shared__ short Qs[32 * 72];
    __shared__ short Ks[2][32 * 72];
    __shared__ short Vt[2][64 * 40];
    __shared__ short Ps[4 * 16 * 40];

    int t = threadIdx.x;
    int s = blockIdx.x, h = blockIdx.y, b = blockIdx.z;
    int nG = *gcount;

    const short* Qb = qh + ((size_t)(b * HH + h) * SS) * HDD;
    const short* Kb = kh + ((size_t)(b * HH + h) * SS) * HDD;
    const short* Vb = vh + ((size_t)(b * HH + h) * SS) * HDD;

    int row8 = t >> 3, dim8 = (t & 7) * 8;
    {
        int cq = row8 < nG ? row8 : 0;
        int src = glist[cq];
        short8 qv = *(const short8*)(Qb + (size_t)src * HDD + dim8);
        *(short8*)&Qs[row8 * 72 + dim8] = qv;
    }
    __syncthreads();

    int lane = t & 63, w = t >> 6;
    int quad = lane >> 4, col = lane & 15;
    int g = w >> 1, qt = w & 1;

    short8 qf0 = *(short8*)&Qs[(qt * 16 + col) * 72 + quad * 8];
    short8 qf1 = *(short8*)&Qs[(qt * 16 + col) * 72 + 32 + quad * 8];

    float4v O0 = {0,0,0,0}, O1 = {0,0,0,0}, O2 = {0,0,0,0}, O3 = {0,0,0,0};
    float lst[4] = {0.f, 0.f, 0.f, 0.f};

    int js0 = s * 256;
    for (int it = 0; it < 4; it++) {
        __syncthreads();
        int r64 = t >> 2, dimb = (t & 3) * 16;
        int j = js0 + it * 64 + r64;
        const short* kp = Kb + (size_t)j * HDD + dimb;
        const short* vp = Vb + (size_t)j * HDD + dimb;
        short8 k0 = *(const short8*)kp, k1 = *(const short8*)(kp + 8);
        short8 v0 = *(const short8*)vp, v1 = *(const short8*)(vp + 8);
        int half = r64 >> 5, r32 = r64 & 31;
        *(short8*)&Ks[half][r32 * 72 + dimb]     = k0;
        *(short8*)&Ks[half][r32 * 72 + dimb + 8] = k1;
        #pragma unroll
        for (int u = 0; u < 8; u++) {
            int d = dimb + u;
            Vt[half][VSL(d, r32)] = v0[u];
        }
        #pragma unroll
        for (int u = 0; u < 8; u++) {
            int d = dimb + 8 + u;
            Vt[half][VSL(d, r32)] = v1[u];
        }
        __syncthreads();

        short8 kA0 = *(short8*)&Ks[g][col * 72 + quad * 8];
        short8 kA1 = *(short8*)&Ks[g][col * 72 + 32 + quad * 8];
        short8 kB0 = *(short8*)&Ks[g][(16 + col) * 72 + quad * 8];
        short8 kB1 = *(short8*)&Ks[g][(16 + col) * 72 + 32 + quad * 8];
        float4v sA = {0,0,0,0}, sB = {0,0,0,0};
        sA = __builtin_amdgcn_mfma_f32_16x16x32_bf16(qf0, kA0, sA, 0, 0, 0);
        sA = __builtin_amdgcn_mfma_f32_16x16x32_bf16(qf1, kA1, sA, 0, 0, 0);
        sB = __builtin_amdgcn_mfma_f32_16x16x32_bf16(qf0, kB0, sB, 0, 0, 0);
        sB = __builtin_amdgcn_mfma_f32_16x16x32_bf16(qf1, kB1, sB, 0, 0, 0);

        #pragma unroll
        for (int r = 0; r < 4; r++) {
            float pa = exp2f(sA[r] * SCALE2);
            float pb = exp2f(sB[r] * SCALE2);
            lst[r] += pa + pb;
            Ps[(w * 16 + quad * 4 + r) * 40 + col]      = f2bf(pa);
            Ps[(w * 16 + quad * 4 + r) * 40 + col + 16] = f2bf(pb);
        }
        asm volatile("s_waitcnt lgkmcnt(0)" ::: "memory");

        short8 pf  = *(short8*)&Ps[(w * 16 + col) * 40 + quad * 8];
        short8 vf0 = *(short8*)&Vt[g][(col) * 40 + ((quad ^ ((col >> 3) & 3)) << 3)];
        short8 vf1 = *(short8*)&Vt[g][(16 + col) * 40 + ((quad ^ (((16 + col) >> 3) & 3)) << 3)];
        short8 vf2 = *(short8*)&Vt[g][(32 + col) * 40 + ((quad ^ (((32 + col) >> 3) & 3)) << 3)];
        short8 vf3 = *(short8*)&Vt[g][(48 + col) * 40 + ((quad ^ (((48 + col) >> 3) & 3)) << 3)];
        O0 = __builtin_amdgcn_mfma_f32_16x16x32_bf16(pf, vf0, O0, 0, 0, 0);
        O1 = __builtin_amdgcn_mfma_f32_16x16x32_bf16(pf, vf1, O1, 0, 0, 0);
        O2 = __builtin_amdgcn_mfma_f32_16x16x32_bf16(pf, vf2, O2, 0, 0, 0);
        O3 = __builtin_amdgcn_mfma_f32_16x16x32_bf16(pf, vf3, O3, 0, 0, 0);
    }

    int sp = s * 2 + g;
    size_t base = ((size_t)(b * HH + h) * 16 + sp) * 32;
    #pragma unroll
    for (int r = 0; r < 4; r++) {
        float l = lst[r];
        #pragma unroll
        for (int mk = 1; mk < 16; mk <<= 1) l += __shfl_xor(l, mk);
        int q = qt * 16 + quad * 4 + r;
        if (col == 0) pl[base + q] = l;
        float* Od = pO + (base + q) * 64;
        Od[col]      = O0[r];
        Od[col + 16] = O1[r];
        Od[col + 32] = O2[r];
        Od[col + 48] = O3[r];
    }
}

// ---------------- merge 16 partials per (b,h): plain sums ----------------
__global__ __launch_bounds__(256)
void global_merge(const float* __restrict__ pl, const float* __restrict__ pO,
                  const int* __restrict__ glist, const int* __restrict__ gcount,
                  short* __restrict__ ao) {
    int h = blockIdx.x, b = blockIdx.y;
    int t = threadIdx.x;
    int d = t & 63, qg = t >> 6;
    int nG = *gcount;
    size_t bh = ((size_t)(b * HH + h) * 16) * 32;

    for (int q = qg; q < nG; q += 4) {
        float L = 0.f, acc = 0.f;
        #pragma unroll
        for (int sp = 0; sp < 16; sp++) {
            L   += pl[bh + sp * 32 + q];
            acc += pO[(bh + sp * 32 + q) * 64 + d];
        }
        int i = glist[q];
        ao[((size_t)b * SS + i) * DMM + h * HDD + d] = f2bf(acc / L);
    }
}

extern "C" void kernel_launch(void* const* d_in, const int* in_sizes, int n_in,
                              void* d_out, int out_size, void* d_ws, size_t ws_size,
                              hipStream_t stream) {
    const float* q  = (const float*)d_in[0];
    const float* k  = (const float*)d_in[1];
    const float* v  = (const float*)d_in[2];
    const float* Wq = (const float*)d_in[3];
    const float* Wk = (const float*)d_in[4];
    const float* Wv = (const float*)d_in[5];
    const float* Wo = (const float*)d_in[6];
    const float* bq = (const float*)d_in[7];
    const float* bk = (const float*)d_in[8];
    const float* bv = (const float*)d_in[9];
    const float* bo = (const float*)d_in[10];
    const int* gidx = (const int*)d_in[11];
    float* out = (float*)d_out;

    // ws (64.03 MB): 32KB hdr | qh,kh,vh,ao bf16 8MB ea | wbf 8MB | abf 24MB (aliased by pl+pO)
    const size_t NE = (size_t)BB * SS * DMM;   // 4M
    const size_t WE = (size_t)DMM * DMM;       // 1M
    int*   g      = (int*)d_ws;
    int*   glist  = g + SS;
    int*   gcount = glist + SS;
    short* qh     = (short*)((char*)d_ws + 32768);
    short* kh     = qh + NE;
    short* vh     = kh + NE;
    short* ao     = vh + NE;
    short* wbf    = ao + NE;
    short* wo     = wbf + 3 * WE;
    short* abf    = wbf + 4 * WE;          // dead after QKV gemm
    float* pl     = (float*)abf;           // alias: written by global_part (later)
    float* pO     = pl + 16384;

    setup_globals<<<1, 256, 0, stream>>>(gidx, g, glist, gcount);

    dim3 gc(2048, 7);
    convert_all<<<gc, 256, 0, stream>>>(q, k, v, Wq, Wk, Wv, Wo, abf, wbf);

    dim3 gq(512, 3);   // batched QKV, 64x128 tiles: 1536 blocks = 6/CU
    gemm64<1, 1><<<gq, 256, 0, stream>>>(abf, wbf, bq, bk, bv, qh, kh, vh);

    band_attn<<<1024, 256, 0, stream>>>(qh, kh, vh, glist, gcount, ao);

    dim3 gp(8, HH, BB);
    global_part<<<gp, 256, 0, stream>>>(qh, kh, vh, glist, gcount, pl, pO);

    dim3 gm(HH, BB);
    global_merge<<<gm, 256, 0, stream>>>(pl, pO, glist, gcount, ao);

    dim3 go(512, 1);   // Wo: 512 blocks = 2/CU
    gemm64<0, 0><<<go, 256, 0, stream>>>(ao, wo, bo, bo, bo, out, out, out);
}